// Round 16
// baseline (174.956 us; speedup 1.0000x reference)
//
#include <hip/hip_runtime.h>

// MultiHeadAttention: B=2, N=2048, C=768, H=12, DH=64. fp32 in/out, bf16 MFMA compute.
// R21 = R20 resubmitted verbatim (previous run died to a container-acquisition
// failure, not a kernel verdict; source re-audited: no OOB, no divergent
// barriers, wave-uniform gload_lds dests, sound vmcnt counting).
// R20 = R19 GEMMs/cvt (== R16-class, best) + attn rebuilt BARRIER-FREE:
//  - QBLK=32, grid 1536 (6 blocks/CU demand, 4 resident at 32.3KB LDS).
//  - Each wave owns a PRIVATE 16-key quarter of every 64-key K/V tile
//    (fragment-order => quarter is a contiguous 2KB range), staged into its
//    own LDS region by its own global_load_lds calls, synced by WAVE-LOCAL
//    counted s_waitcnt vmcnt(4) (T4) -- ZERO __syncthreads in the K-loop.
//  - Cross-wave O/lsum reduction once at the end via LDS exchange (2 barriers).
//  - rule #18: sched_barrier(0) after each vmcnt asm; rule #20: no runtime
//    register-array indices (runtime w only in LDS addresses / selects).

typedef __bf16 bf16_t;
typedef __bf16 bf16x8 __attribute__((ext_vector_type(8)));
typedef __bf16 bf16x4 __attribute__((ext_vector_type(4)));
typedef short  short4_t __attribute__((ext_vector_type(4)));
typedef float  floatx4 __attribute__((ext_vector_type(4)));

#define MFMA32(a, b, c) __builtin_amdgcn_mfma_f32_16x16x32_bf16(a, b, c, 0, 0, 0)
#define MFMA16(a, b, c) __builtin_amdgcn_mfma_f32_16x16x16bf16_1k(a, b, c, 0, 0, 0)

__device__ __forceinline__ void gload16(const bf16_t* g, bf16_t* l) {
  __builtin_amdgcn_global_load_lds(
      (__attribute__((address_space(1))) void*)g,
      (__attribute__((address_space(3))) void*)l, 16, 0, 0);
}

// ---------------------------------------------------------------- converts --
// One kernel, 1D grid 3648: blocks [0,3072) convert x fp32->bf16 (vectorized);
// blocks [3072,3648) transpose+convert the 4 weight matrices (64x64 LDS tiles).
__global__ __launch_bounds__(256) void cvt_all_kernel(
    const float* __restrict__ x, const float* __restrict__ W0,
    const float* __restrict__ W1, const float* __restrict__ W2,
    const float* __restrict__ W3, bf16_t* __restrict__ xb,
    bf16_t* __restrict__ T0, bf16_t* __restrict__ T1,
    bf16_t* __restrict__ T2, bf16_t* __restrict__ T3) {
  __shared__ bf16_t T[64][65];
  const int id = blockIdx.x;
  if (id < 3072) {
    int i = id * 256 + threadIdx.x;
    floatx4 v = ((const floatx4*)x)[i];
    bf16x4 o;
    o[0] = (bf16_t)v[0]; o[1] = (bf16_t)v[1]; o[2] = (bf16_t)v[2]; o[3] = (bf16_t)v[3];
    ((bf16x4*)xb)[i] = o;
    return;
  }
  const int wid = id - 3072;              // 0..575
  const int z = wid / 144, rem = wid % 144;
  const int by = rem / 12, bx = rem % 12;
  const float* W = (z == 0) ? W0 : (z == 1) ? W1 : (z == 2) ? W2 : W3;
  bf16_t* WT = (z == 0) ? T0 : (z == 1) ? T1 : (z == 2) ? T2 : T3;
  const int c = threadIdx.x & 63, r0 = threadIdx.x >> 6;
  const int i0 = by * 64, o0 = bx * 64;
#pragma unroll
  for (int p = 0; p < 16; ++p) {
    int r = p * 4 + r0;
    T[r][c] = (bf16_t)W[(i0 + r) * 768 + o0 + c];
  }
  __syncthreads();
#pragma unroll
  for (int p = 0; p < 16; ++p) {
    int r = p * 4 + r0;
    WT[(o0 + r) * 768 + i0 + c] = T[c][r];
  }
}

// ------------------------------------------------------------------- GEMMs --
#define LDPG 72  // BK=64 + 8 pad

// Fragment-order layouts (per bh = b*12+h, per 128-key tile kt):
//  K: elem(key,d) -> kt*8192 + ((nk*2+kk)*64 + quad*16 + l15)*8 + j
//     nk=key128>>4, l15=key128&15, kk=d>>5, quad=(d>>3)&3, j=d&7
//  V: elem(key,d) -> kt*8192 + ((nk*4+nd)*64 + vq*16 + vl15)*4 + j
//     nk=key128>>4, vq=(key128>>2)&3, j=key128&3, nd=d>>4, vl15=d&15

// T14 staging: LOADSET issues 8 independent global loads into NAMED regs;
// WRITESET commits them to LDS buffer (LA/LB) an iteration later.
#define LOADSET(KT)                                        \
  sa0 = *(const bf16x8*)(gA + (KT));                       \
  sa1 = *(const bf16x8*)(gA + (KT) + 32 * 768);            \
  sa2 = *(const bf16x8*)(gA + (KT) + 64 * 768);            \
  sa3 = *(const bf16x8*)(gA + (KT) + 96 * 768);            \
  sb0 = *(const bf16x8*)(gB + (KT));                       \
  sb1 = *(const bf16x8*)(gB + (KT) + 32 * 768);            \
  sb2 = *(const bf16x8*)(gB + (KT) + 64 * 768);            \
  sb3 = *(const bf16x8*)(gB + (KT) + 96 * 768);

#define WRITESET(LA, LB)                                   \
  *(bf16x8*)(LA) = sa0;                                    \
  *(bf16x8*)((LA) + 32 * LDPG) = sa1;                      \
  *(bf16x8*)((LA) + 64 * LDPG) = sa2;                      \
  *(bf16x8*)((LA) + 96 * LDPG) = sa3;                      \
  *(bf16x8*)(LB) = sb0;                                    \
  *(bf16x8*)((LB) + 32 * LDPG) = sb1;                      \
  *(bf16x8*)((LB) + 64 * LDPG) = sb2;                      \
  *(bf16x8*)((LB) + 96 * LDPG) = sb3;

#define GCOMPUTE(BUF)                                                       \
  {                                                                         \
    _Pragma("unroll") for (int kk2 = 0; kk2 < 2; ++kk2) {                   \
      bf16x8 af[4], bfr[4];                                                 \
      _Pragma("unroll") for (int i = 0; i < 4; ++i) {                       \
        af[i]  = *(bf16x8*)&Al[BUF][(wr * 64 + i * 16 + l15) * LDPG +       \
                                    kk2 * 32 + quad * 8];                   \
        bfr[i] = *(bf16x8*)&Bl[BUF][(wc * 64 + i * 16 + l15) * LDPG +       \
                                    kk2 * 32 + quad * 8];                   \
      }                                                                     \
      _Pragma("unroll") for (int mi = 0; mi < 4; ++mi)                      \
          _Pragma("unroll") for (int ni = 0; ni < 4; ++ni)                  \
              acc[mi][ni] = MFMA32(af[mi], bfr[ni], acc[mi][ni]);           \
    }                                                                       \
  }

// K-loop: LDS dbuf, 1 barrier per 64-tile, loads issued ~1.5 phases early.
#define GEMM_KLOOP()                                       \
  LOADSET(0);                                              \
  WRITESET(lA0, lB0);                                      \
  LOADSET(64);                                             \
  __syncthreads();                                         \
  for (int t = 0; t < 12; t += 2) {                        \
    GCOMPUTE(0);                                           \
    WRITESET(lA1, lB1);        /* tile t+1 */              \
    if (t + 2 < 12) LOADSET((t + 2) * 64);                 \
    __syncthreads();                                       \
    GCOMPUTE(1);                                           \
    if (t + 2 < 12) {                                      \
      WRITESET(lA0, lB0);      /* tile t+2 */              \
      if (t + 3 < 12) LOADSET((t + 3) * 64);               \
    }                                                      \
    __syncthreads();                                       \
  }

// Fused QKV, M = output channels (768), N = tokens (4096).  Grid (32,6,3).
__global__ __launch_bounds__(256, 2) void gemm_qkv(
    const bf16_t* __restrict__ Xb, const bf16_t* __restrict__ WqT,
    const bf16_t* __restrict__ WkT, const bf16_t* __restrict__ WvT,
    const float* __restrict__ bq, const float* __restrict__ bk,
    const float* __restrict__ bv, bf16_t* __restrict__ qw,
    bf16_t* __restrict__ kw, bf16_t* __restrict__ vtw) {
  __shared__ bf16_t Al[2][128 * LDPG];
  __shared__ bf16_t Bl[2][128 * LDPG];
  const int z = blockIdx.z;
  const bf16_t* Wt = (z == 0) ? WqT : (z == 1) ? WkT : WvT;
  const float* bias = (z == 0) ? bq : (z == 1) ? bk : bv;
  const float oscale = (z == 0) ? 0.18033688011112042f : 1.0f;  // 0.125*log2(e)

  const int tid = threadIdx.x, lane = tid & 63, w = tid >> 6;
  const int wr = w >> 1, wc = w & 1;
  const int l15 = lane & 15, quad = lane >> 4;
  const int m0 = blockIdx.y * 128, n0 = blockIdx.x * 128;

  const int r0 = tid >> 3, q0c = (tid & 7) * 8;
  const bf16_t* gA = &Wt[(m0 + r0) * 768 + q0c];
  const bf16_t* gB = &Xb[(n0 + r0) * 768 + q0c];
  bf16_t* lA0 = &Al[0][r0 * LDPG + q0c];
  bf16_t* lB0 = &Bl[0][r0 * LDPG + q0c];
  bf16_t* lA1 = &Al[1][r0 * LDPG + q0c];
  bf16_t* lB1 = &Bl[1][r0 * LDPG + q0c];

  floatx4 acc[4][4] = {};
  bf16x8 sa0, sa1, sa2, sa3, sb0, sb1, sb2, sb3;   // staging regs (single set)

  GEMM_KLOOP();

  const int hh = (m0 + wr * 64) >> 6;  // head (64-aligned per wave-row)
#pragma unroll
  for (int mi = 0; mi < 4; ++mi) {
    const int d0 = mi * 16 + quad * 4;           // d within head, multiple of 4
    const int gm0 = m0 + wr * 64 + d0;
    float bv4[4];
#pragma unroll
    for (int r = 0; r < 4; ++r) bv4[r] = bias[gm0 + r];
#pragma unroll
    for (int ni = 0; ni < 4; ++ni) {
      const int gn = n0 + wc * 64 + ni * 16 + l15;
      const int bb = gn >> 11, tok = gn & 2047;
      const int bh = bb * 12 + hh;
      if (z == 0) {
        bf16x4 pk;
#pragma unroll
        for (int r = 0; r < 4; ++r)
          pk[r] = (bf16_t)((acc[mi][ni][r] + bv4[r]) * oscale);
        *(bf16x4*)&qw[bh * 131072 + tok * 64 + d0] = pk;
      } else if (z == 1) {
        const int kt2 = tok >> 7, k128 = tok & 127;
        const int nk = k128 >> 4, kl15 = k128 & 15;
        const int kk = d0 >> 5, kq = (d0 >> 3) & 3, j0 = d0 & 7;
        bf16x4 pk;
#pragma unroll
        for (int r = 0; r < 4; ++r)
          pk[r] = (bf16_t)(acc[mi][ni][r] + bv4[r]);
        *(bf16x4*)&kw[bh * 131072 + kt2 * 8192 +
                      ((nk * 2 + kk) * 64 + kq * 16 + kl15) * 8 + j0] = pk;
      } else {
        const int kt2 = tok >> 7, k128 = tok & 127;
        const int nk = k128 >> 4, vq = (k128 >> 2) & 3, j = k128 & 3;
        const int nd = d0 >> 4, vl0 = d0 & 15;
        const int base = bh * 131072 + kt2 * 8192 +
                         ((nk * 4 + nd) * 64 + vq * 16 + vl0) * 4 + j;
#pragma unroll
        for (int r = 0; r < 4; ++r)
          vtw[base + r * 4] = (bf16_t)(acc[mi][ni][r] + bv4[r]);
      }
    }
  }
}

// Output projection, M = channels: out fp32 [4096 tok][768 ch].  Grid (32,6).
__global__ __launch_bounds__(256, 2) void gemm_proj(
    const bf16_t* __restrict__ Yb, const bf16_t* __restrict__ WpT,
    const float* __restrict__ bias, float* __restrict__ out) {
  __shared__ bf16_t Al[2][128 * LDPG];
  __shared__ bf16_t Bl[2][128 * LDPG];
  const int tid = threadIdx.x, lane = tid & 63, w = tid >> 6;
  const int wr = w >> 1, wc = w & 1;
  const int l15 = lane & 15, quad = lane >> 4;
  const int m0 = blockIdx.y * 128, n0 = blockIdx.x * 128;

  const int r0 = tid >> 3, q0c = (tid & 7) * 8;
  const bf16_t* gA = &WpT[(m0 + r0) * 768 + q0c];
  const bf16_t* gB = &Yb[(n0 + r0) * 768 + q0c];
  bf16_t* lA0 = &Al[0][r0 * LDPG + q0c];
  bf16_t* lB0 = &Bl[0][r0 * LDPG + q0c];
  bf16_t* lA1 = &Al[1][r0 * LDPG + q0c];
  bf16_t* lB1 = &Bl[1][r0 * LDPG + q0c];

  floatx4 acc[4][4] = {};
  bf16x8 sa0, sa1, sa2, sa3, sb0, sb1, sb2, sb3;

  GEMM_KLOOP();

#pragma unroll
  for (int mi = 0; mi < 4; ++mi) {
    const int gm0 = m0 + wr * 64 + mi * 16 + quad * 4;
    floatx4 bv4;
#pragma unroll
    for (int r = 0; r < 4; ++r) bv4[r] = bias[gm0 + r];
#pragma unroll
    for (int ni = 0; ni < 4; ++ni) {
      const int gn = n0 + wc * 64 + ni * 16 + l15;
      floatx4 v = acc[mi][ni] + bv4;
      *(floatx4*)&out[gn * 768 + gm0] = v;
    }
  }
}

// --------------------------------------------------------------- attention --
// Block: one (b,h) x 32 Q rows; grid 1536 (XCD x owns bh in [3x,3x+3)).
// Wave w owns the 16-key group g=w of every 64-key tile (fragment order ->
// contiguous 2KB K + 2KB V), staged into its PRIVATE LDS dbuf region by its
// own global_load_lds; wave-local counted vmcnt(4) -- no barriers in K-loop.
// Cross-wave (key-group) reduction of O and lsum at the end via LDS exchange.
__global__ __launch_bounds__(256, 4) void attn_kernel(
    const bf16_t* __restrict__ Q, const bf16_t* __restrict__ Kf,
    const bf16_t* __restrict__ Vf, bf16_t* __restrict__ Y) {
  // E: 32KB. K-loop: wave w's dbuf at elems [w*4096, w*4096+4096) of (bf16*)E
  //   (buf b at +b*2048: K [0,1024), V [1024,2048)).
  // End: exchange chunks E[((s*2+ni)*3+ndl)*256 + lane*4] (floats, 24KB used).
  __shared__ __align__(16) float E[8192];
  __shared__ float Ls[4][2][16];   // [src wave][ni][q&15]

  const int tid = threadIdx.x, lane = tid & 63, w = tid >> 6;
  const int l15 = lane & 15, quad = lane >> 4;

  // XCD-aware mapping: block i -> XCD i&7; XCD x owns bh in [3x,3x+3).
  const int i = blockIdx.x;            // 0..1535
  const int xcd = i & 7, j = i >> 3;   // j: 0..191
  const int bh = xcd * 3 + (j >> 6);
  const int q0 = (j & 63) * 32;

  const bf16_t* Qb = Q + bh * 131072;
  // wave-private staging bases: group g=w of each tile = elems [w*1024,+1024)
  const bf16_t* Kg = Kf + bh * 131072 + w * 1024 + lane * 8;
  const bf16_t* Vg = Vf + bh * 131072 + w * 1024 + lane * 8;
  bf16_t* kv = (bf16_t*)E;
  bf16_t* kvw = kv + w * 4096 + lane * 8;   // + b*2048 per buffer

  // Q B-frags: n=q over l15, k=dh over quad*8+j.  32 q rows (ni=0,1).
  bf16x8 qf[2][2];
#pragma unroll
  for (int ni = 0; ni < 2; ++ni)
#pragma unroll
    for (int kk = 0; kk < 2; ++kk)
      qf[ni][kk] = *(const bf16x8*)&Qb[(q0 + ni * 16 + l15) * 64 +
                                       kk * 32 + quad * 8];

  floatx4 oacc[2][4] = {};   // [ni(q16)][nd(d16)] partial over THIS WAVE's keys
  floatx4 sacc[2] = {};      // row-sums via MFMA ones-trick
  const short4_t ones = {0x3F80, 0x3F80, 0x3F80, 0x3F80};  // bf16 1.0 x4

  // stage this wave's 16-key group of tile t into its private buf b (4 gload16)
  auto stage = [&](int b, int t) {
    const bf16_t* kg = Kg + t * 4096;
    const bf16_t* vg = Vg + t * 4096;
    bf16_t* d = kvw + b * 2048;
    gload16(kg, d);
    gload16(kg + 512, d + 512);
    gload16(vg, d + 1024);
    gload16(vg + 512, d + 1536);
  };

  auto compute = [&](int b) {
    const bf16_t* Kl = kv + w * 4096 + b * 2048;
    const bf16_t* Vl = Kl + 1024;
    // S^T = K*Q^T (16 keys x 32 q); P = exp2 packed to x16 A-frags
    // (m=q=l15, k=key=quad*4+r).
    short4_t pk[2];
#pragma unroll
    for (int ni = 0; ni < 2; ++ni) {
      floatx4 s = {};
#pragma unroll
      for (int kk = 0; kk < 2; ++kk) {
        bf16x8 kfr = *(const bf16x8*)&Kl[kk * 512 + lane * 8];
        s = MFMA32(kfr, qf[ni][kk], s);
      }
      bf16x4 ph;
#pragma unroll
      for (int r = 0; r < 4; ++r)
        ph[r] = (bf16_t)__builtin_amdgcn_exp2f(s[r]);
      pk[ni] = __builtin_bit_cast(short4_t, ph);
    }
    // O += P*V; sacc += P*1 (row-sums on the MFMA pipe).
#pragma unroll
    for (int nd = 0; nd < 4; ++nd) {
      bf16x4 vfr = *(const bf16x4*)&Vl[nd * 256 + lane * 4];
      short4_t vs = __builtin_bit_cast(short4_t, vfr);
#pragma unroll
      for (int ni = 0; ni < 2; ++ni)
        oacc[ni][nd] = MFMA16(pk[ni], vs, oacc[ni][nd]);
    }
#pragma unroll
    for (int ni = 0; ni < 2; ++ni)
      sacc[ni] = MFMA16(pk[ni], ones, sacc[ni]);
  };

  // Zero-barrier K-loop: wave-local counted vmcnt.  Steady state: 8 loads in
  // flight (tile t, tile t+1); vmcnt(4) retires tile t's 4 before compute(t).
  stage(0, 0);
  for (int t = 0; t < 31; ++t) {
    stage((t + 1) & 1, t + 1);
    asm volatile("s_waitcnt vmcnt(4)" ::: "memory");
    __builtin_amdgcn_sched_barrier(0);
    compute(t & 1);
  }
  asm volatile("s_waitcnt vmcnt(0)" ::: "memory");
  __builtin_amdgcn_sched_barrier(0);
  compute(1);   // t=31

  // lsum: sacc[ni][r] = this wave's total for q = ni*16 + quad*4 + r
  // (uniform across l15).
  if (l15 == 0) {
#pragma unroll
    for (int ni = 0; ni < 2; ++ni)
#pragma unroll
      for (int r = 0; r < 4; ++r)
        Ls[w][ni][quad * 4 + r] = sacc[ni][r];
  }

  __syncthreads();   // all waves done with their private KV reads; E reusable

  // Each wave writes its partials for the 3 d-quarters it does NOT own
  // (owner of nd is wave nd).  Chunk (src s, ni, ndl) at ((s*2+ni)*3+ndl)*256.
#pragma unroll
  for (int ni = 0; ni < 2; ++ni)
#pragma unroll
    for (int nd = 0; nd < 4; ++nd) {
      if (nd != w) {
        const int ndl = nd - (nd > w ? 1 : 0);       // runtime, address only
        *(floatx4*)&E[(((w * 2 + ni) * 3 + ndl) * 64 + lane) * 4] = oacc[ni][nd];
      }
    }
  __syncthreads();

  const int bb = bh / 12, h = bh % 12;
#pragma unroll
  for (int ni = 0; ni < 2; ++ni) {
    float tot[4];
#pragma unroll
    for (int r = 0; r < 4; ++r)
      tot[r] = Ls[0][ni][quad * 4 + r] + Ls[1][ni][quad * 4 + r] +
               Ls[2][ni][quad * 4 + r] + Ls[3][ni][quad * 4 + r];
    // my own partial for owned quarter nd == w (compile-time-indexed select)
    floatx4 o = (w == 0) ? oacc[ni][0]
              : (w == 1) ? oacc[ni][1]
              : (w == 2) ? oacc[ni][2]
                         : oacc[ni][3];
#pragma unroll
    for (int s = 0; s < 4; ++s) {
      if (s != w) {
        const int ndl = w - (w > s ? 1 : 0);         // runtime, address only
        o += *(const floatx4*)&E[(((s * 2 + ni) * 3 + ndl) * 64 + lane) * 4];
      }
    }
#pragma unroll
    for (int r = 0; r < 4; ++r) {
      const int tok = q0 + ni * 16 + quad * 4 + r;
      const int col = h * 64 + w * 16 + l15;
      Y[(bb * 2048 + tok) * 768 + col] = (bf16_t)(o[r] / tot[r]);
    }
  }
}

// ------------------------------------------------------------------ launch --
extern "C" void kernel_launch(void* const* d_in, const int* in_sizes, int n_in,
                              void* d_out, int out_size, void* d_ws, size_t ws_size,
                              hipStream_t stream) {
  const float* x  = (const float*)d_in[0];
  const float* Wq = (const float*)d_in[1];
  const float* bq = (const float*)d_in[2];
  const float* Wk = (const float*)d_in[3];
  const float* bk = (const float*)d_in[4];
  const float* Wv = (const float*)d_in[5];
  const float* bv = (const float*)d_in[6];
  const float* Wp = (const float*)d_in[7];
  const float* bp = (const float*)d_in[8];
  float* out = (float*)d_out;

  char* ws = (char*)d_ws;
  bf16_t* xb  = (bf16_t*)ws; ws += (size_t)4096 * 768 * 2;
  bf16_t* WqT = (bf16_t*)ws; ws += (size_t)768 * 768 * 2;
  bf16_t* WkT = (bf16_t*)ws; ws += (size_t)768 * 768 * 2;
  bf16_t* WvT = (bf16_t*)ws; ws += (size_t)768 * 768 * 2;
  bf16_t* WpT = (bf16_t*)ws; ws += (size_t)768 * 768 * 2;
  bf16_t* qw  = (bf16_t*)ws; ws += (size_t)24 * 2048 * 64 * 2;
  bf16_t* kw  = (bf16_t*)ws; ws += (size_t)24 * 2048 * 64 * 2;
  bf16_t* vtw = (bf16_t*)ws; ws += (size_t)24 * 2048 * 64 * 2;
  bf16_t* yw  = (bf16_t*)ws; ws += (size_t)4096 * 768 * 2;

  cvt_all_kernel<<<3648, 256, 0, stream>>>(x, Wq, Wk, Wv, Wp, xb, WqT, WkT, WvT, WpT);
  gemm_qkv<<<dim3(32, 6, 3), 256, 0, stream>>>(xb, WqT, WkT, WvT, bq, bk, bv, qw, kw, vtw);
  attn_kernel<<<1536, 256, 0, stream>>>(qw, kw, vtw, yw);
  gemm_proj<<<dim3(32, 6), 256, 0, stream>>>(yw, WpT, bp, out);
}